// Round 4
// baseline (1578.589 us; speedup 1.0000x reference)
//
#include <hip/hip_runtime.h>
#include <hip/hip_bf16.h>
#include <stdint.h>
#include <stddef.h>

// Problem sizes (fixed by the reference)
#define B_SZ 512
#define S_SZ 64
#define E_SZ 512
#define H_SZ 1024
#define V_SZ 1024
#define C_SZ 1000

typedef __hip_bfloat16 bf16;
typedef __attribute__((ext_vector_type(8))) __bf16 bf16x8;
typedef __attribute__((ext_vector_type(4))) float f32x4;

// ---- workspace layout (bytes), total 76 MB ----
#define EMB_OFF   (0ull)          // emb_w bf16    [1024][512]  1 MB  (dead after xproj;
                                  //   bytes 0..3 = emb row 0 (PAD, all-zero) reused as
                                  //   the grid-barrier counter by the fused kernel)
#define WIH_OFF   (1ull << 20)    // w_ih  bf16    [1024][512]  1 MB
#define WHH_OFF   (2ull << 20)    // w_hh  bf16    [1024][1024] 2 MB
#define FC1_OFF   (4ull << 20)    // fc1_w bf16    [1024][1024] 2 MB
#define FC2_OFF   (6ull << 20)    // fc2_w bf16    [1024][1024] 2 MB (rows >=1000 zero)
#define H0_OFF    (8ull << 20)    // h buf 0 bf16  [512][1024]  1 MB
#define H1_OFF    (9ull << 20)    // h buf 1 bf16  [512][1024]  1 MB
#define YL_OFF    (10ull << 20)   // y_last bf16   [512][1024]  1 MB
#define Y1_OFF    (11ull << 20)   // fc1 out bf16  [512][1024]  1 MB
#define XP_OFF    (12ull << 20)   // x_proj bf16   [64][512][1024] 64 MB

// async global->LDS, 16B/lane. HW writes lane l at lds_base + l*16 (linear,
// wave-uniform base). Swizzled layouts: pre-swizzle the per-lane GLOBAL source
// chunk (rule #21: linear dest + inv-swz source + swz on read; XOR self-inverse).
__device__ __forceinline__ void gl_lds16(const void* g, void* l) {
  __builtin_amdgcn_global_load_lds(
      (const __attribute__((address_space(1))) unsigned int*)g,
      (__attribute__((address_space(3))) unsigned int*)l, 16, 0, 0);
}

// ---------------------------------------------------------------------------
// prep: fp32 -> bf16 weight conversion + zero-init h0 + zero-pad fc2 rows.
// Forces emb row 0 to exact zeros (PAD row; also the barrier counter bytes).
// ---------------------------------------------------------------------------
__global__ __launch_bounds__(256) void prep_kernel(
    const float* __restrict__ emb_w, const float* __restrict__ w_ih,
    const float* __restrict__ w_hh, const float* __restrict__ fc1_w,
    const float* __restrict__ fc2_w, char* __restrict__ ws) {
  bf16* emb = (bf16*)(ws + EMB_OFF);
  bf16* wih = (bf16*)(ws + WIH_OFF);
  bf16* whh = (bf16*)(ws + WHH_OFF);
  bf16* fc1 = (bf16*)(ws + FC1_OFF);
  bf16* fc2 = (bf16*)(ws + FC2_OFF);
  bf16* h0  = (bf16*)(ws + H0_OFF);

  const long N_EMB = 524288;   // 1024*512
  const long N_WIH = 524288;
  const long N_WHH = 1048576;  // 1024*1024
  const long N_FC1 = 1048576;
  const long N_FC2 = 1048576;  // padded to 1024 rows
  const long N_H0  = 524288;   // 512*1024
  const long TOTAL = N_EMB + N_WIH + N_WHH + N_FC1 + N_FC2 + N_H0;

  long stride = (long)gridDim.x * blockDim.x;
  for (long i = (long)blockIdx.x * blockDim.x + threadIdx.x; i < TOTAL; i += stride) {
    long j = i;
    if (j < N_EMB) {
      // row 0 forced to zero: PAD row per reference; bytes 0..3 double as the
      // fused kernel's grid-barrier counter (must start at 0).
      emb[j] = (j < E_SZ) ? __float2bfloat16(0.f) : __float2bfloat16(emb_w[j]);
      continue;
    }
    j -= N_EMB;
    if (j < N_WIH) { wih[j] = __float2bfloat16(w_ih[j]); continue; }
    j -= N_WIH;
    if (j < N_WHH) { whh[j] = __float2bfloat16(w_hh[j]); continue; }
    j -= N_WHH;
    if (j < N_FC1) { fc1[j] = __float2bfloat16(fc1_w[j]); continue; }
    j -= N_FC1;
    if (j < N_FC2) {
      fc2[j] = (j < (long)C_SZ * H_SZ) ? __float2bfloat16(fc2_w[j]) : __float2bfloat16(0.f);
      continue;
    }
    j -= N_FC2;
    h0[j] = __float2bfloat16(0.f);
  }
}

// ---------------------------------------------------------------------------
// xproj: xp[s][b][h] = sum_e emb[x_in[b][s]][e] * w_ih[h][e] + b_ih[h]
// GEMM M=32768 (r=s*512+b), N=1024, K=512. Tile 128x128, BK=64, 4 waves,
// double-buffered + XOR-swizzled LDS, gather folded into staging addresses.
// (round 2: 46.6 us, bank conflicts = 0, passed)
// ---------------------------------------------------------------------------
__global__ __launch_bounds__(256) void xproj_kernel(
    const int* __restrict__ x_in, const float* __restrict__ b_ih,
    char* __restrict__ ws) {
  const bf16* emb = (const bf16*)(ws + EMB_OFF);
  const bf16* wih = (const bf16*)(ws + WIH_OFF);
  bf16* xp = (bf16*)(ws + XP_OFF);

  __shared__ bf16 Asm[2][128][64];  // 16 KB per buffer
  __shared__ bf16 Bsm[2][128][64];

  const int tid = threadIdx.x;
  const int lane = tid & 63;
  const int wid = tid >> 6;
  const int mb = blockIdx.x >> 3;  // 0..255
  const int nb = blockIdx.x & 7;   // 0..7
  const int rowBase = mb * 128;
  const int colBase = nb * 128;
  const int s = rowBase >> 9;      // whole 128-row tile shares one s

  const int lrow = lane >> 3;      // 0..7
  const int lchk = lane & 7;       // 0..7 (8-bf16 chunks)

  int tok[4];
#pragma unroll
  for (int i = 0; i < 4; ++i) {
    int rt = wid * 32 + i * 8 + lrow;
    int b = (rowBase + rt) & 511;
    tok[i] = x_in[b * S_SZ + s];
  }

  const int wr = wid >> 1, wc = wid & 1;
  f32x4 acc[4][4];
#pragma unroll
  for (int i = 0; i < 4; ++i)
#pragma unroll
    for (int j = 0; j < 4; ++j) acc[i][j] = (f32x4){0.f, 0.f, 0.f, 0.f};

  auto stage = [&](int buf, int k0) {
#pragma unroll
    for (int i = 0; i < 4; ++i) {
      int rt = wid * 32 + i * 8;                      // wave-uniform
      int sc = (lchk ^ ((rt + lrow) & 7)) * 8;        // inv-swizzled source
      gl_lds16(emb + (size_t)tok[i] * E_SZ + k0 + sc, &Asm[buf][rt][0]);
    }
#pragma unroll
    for (int i = 0; i < 4; ++i) {
      int rt = wid * 32 + i * 8;
      int sc = (lchk ^ ((rt + lrow) & 7)) * 8;
      gl_lds16(wih + (size_t)(colBase + rt + lrow) * E_SZ + k0 + sc, &Bsm[buf][rt][0]);
    }
  };

  stage(0, 0);
  __syncthreads();
  int cur = 0;
  for (int t8 = 0; t8 < 8; ++t8) {   // K = 8 * 64
    if (t8 < 7) stage(cur ^ 1, (t8 + 1) * 64);
#pragma unroll
    for (int kk = 0; kk < 2; ++kk) {
      const int kfc = kk * 4 + (lane >> 4);  // chunk index 0..7
      bf16x8 a[4], b[4];
#pragma unroll
      for (int i = 0; i < 4; ++i) {
        int r = wr * 64 + i * 16 + (lane & 15);
        a[i] = *(const bf16x8*)&Asm[cur][r][(kfc ^ (r & 7)) * 8];
      }
#pragma unroll
      for (int j = 0; j < 4; ++j) {
        int r = wc * 64 + j * 16 + (lane & 15);
        b[j] = *(const bf16x8*)&Bsm[cur][r][(kfc ^ (r & 7)) * 8];
      }
#pragma unroll
      for (int i = 0; i < 4; ++i)
#pragma unroll
        for (int j = 0; j < 4; ++j)
          acc[i][j] = __builtin_amdgcn_mfma_f32_16x16x32_bf16(a[i], b[j], acc[i][j], 0, 0, 0);
    }
    __syncthreads();  // implicit vmcnt(0)+lgkmcnt(0): dbuf safe w/ 1 barrier
    cur ^= 1;
  }

  const int crow = (lane >> 4) * 4;
  const int ccol = lane & 15;
#pragma unroll
  for (int j = 0; j < 4; ++j) {
    const int col = colBase + wc * 64 + j * 16 + ccol;
    const float bias = b_ih[col];
#pragma unroll
    for (int i = 0; i < 4; ++i) {
      const int r0 = rowBase + wr * 64 + i * 16 + crow;
#pragma unroll
      for (int reg = 0; reg < 4; ++reg) {
        float v = acc[i][j][reg] + bias;
        xp[(size_t)(r0 + reg) * H_SZ + col] = __float2bfloat16(v);
      }
    }
  }
}

// ---------------------------------------------------------------------------
// gemm_tile: one 32x64 output tile, K=1024, BK=128, 4 waves (2x2 of 16x32),
// double-buffered + XOR-swizzled LDS. Exact math from round-2's gemm32
// (passed, bank-conflict-free).
// MODE 0: h_out = tanh(A@B^T + xp_t + bias); capture y_last at t==len-1
// MODE 1: out = relu(A@B^T + bias) -> bf16
// MODE 2: out = A@B^T + bias -> fp32 (cols < 1000)
// ---------------------------------------------------------------------------
template <int MODE>
__device__ __forceinline__ void gemm_tile(
    const bf16* __restrict__ A, const bf16* __restrict__ Bw,
    const float* __restrict__ bias, const bf16* __restrict__ xp_t,
    const int* __restrict__ lens, int t,
    bf16* __restrict__ hout, bf16* __restrict__ yl, float* __restrict__ out_f32,
    bf16 (&Asm)[2][32][128], bf16 (&Bsm)[2][64][128],
    int tid, int rowBase, int colBase) {
  const int lane = tid & 63;
  const int wid = tid >> 6;
  const int wr = wid >> 1, wc = wid & 1;

  const int lrow = lane >> 4;      // 0..3
  const int lchk = lane & 15;      // 0..15 (8-bf16 chunks)

  f32x4 acc[2];
#pragma unroll
  for (int j = 0; j < 2; ++j) acc[j] = (f32x4){0.f, 0.f, 0.f, 0.f};

  auto stage = [&](int buf, int k0) {
#pragma unroll
    for (int i = 0; i < 2; ++i) {                      // A: 8 rows per wave
      int rt = wid * 8 + i * 4;                        // wave-uniform
      int sc = (lchk ^ ((rt + lrow) & 7)) * 8;         // inv-swizzled source
      gl_lds16(A + (size_t)(rowBase + rt + lrow) * H_SZ + k0 + sc, &Asm[buf][rt][0]);
    }
#pragma unroll
    for (int i = 0; i < 4; ++i) {                      // B: 16 rows per wave
      int rt = wid * 16 + i * 4;
      int sc = (lchk ^ ((rt + lrow) & 7)) * 8;
      gl_lds16(Bw + (size_t)(colBase + rt + lrow) * H_SZ + k0 + sc, &Bsm[buf][rt][0]);
    }
  };

  stage(0, 0);
  __syncthreads();
  int cur = 0;
  for (int t8 = 0; t8 < 8; ++t8) {   // K = 8 * 128
    if (t8 < 7) stage(cur ^ 1, (t8 + 1) * 128);
#pragma unroll
    for (int kc = 0; kc < 4; ++kc) {
      const int kfc = kc * 4 + (lane >> 4);  // chunk index 0..15
      const int ra = wr * 16 + (lane & 15);
      bf16x8 a = *(const bf16x8*)&Asm[cur][ra][(kfc ^ (ra & 7)) * 8];
#pragma unroll
      for (int j = 0; j < 2; ++j) {
        const int rb = wc * 32 + j * 16 + (lane & 15);
        bf16x8 b = *(const bf16x8*)&Bsm[cur][rb][(kfc ^ (rb & 7)) * 8];
        acc[j] = __builtin_amdgcn_mfma_f32_16x16x32_bf16(a, b, acc[j], 0, 0, 0);
      }
    }
    __syncthreads();
    cur ^= 1;
  }

  const int crow = (lane >> 4) * 4;
  const int ccol = lane & 15;
#pragma unroll
  for (int j = 0; j < 2; ++j) {
    const int col = colBase + wc * 32 + j * 16 + ccol;
    const float bv = (MODE == 2 && col >= C_SZ) ? 0.f : bias[col];
#pragma unroll
    for (int reg = 0; reg < 4; ++reg) {
      const int row = rowBase + wr * 16 + crow + reg;
      float v = acc[j][reg] + bv;
      if (MODE == 0) {
        v += __bfloat162float(xp_t[(size_t)row * H_SZ + col]);
        float h = tanhf(v);
        bf16 hb = __float2bfloat16(h);
        hout[(size_t)row * H_SZ + col] = hb;
        if (t == lens[row] - 1) yl[(size_t)row * H_SZ + col] = hb;
      } else if (MODE == 1) {
        v = fmaxf(v, 0.f);
        hout[(size_t)row * H_SZ + col] = __float2bfloat16(v);
      } else {
        if (col < C_SZ) out_f32[(size_t)row * C_SZ + col] = v;
      }
    }
  }
}

// ---------------------------------------------------------------------------
// Grid barrier (monotonic counting). All 256 WGs are guaranteed co-resident:
// 48 KB LDS -> >=1 WG/CU capacity, grid(256) <= CUs(256), so every WG is
// scheduled before any can block. Release ordering on the add publishes this
// WG's h-stores agent-wide (L2 writeback); acquire on the spin-load
// invalidates stale lines before the next step reads h. No separate fence
// builtin needed (ROCm here lacks __hip_atomic_fence).
// ---------------------------------------------------------------------------
__device__ __forceinline__ void gridbar(unsigned* bar, unsigned target) {
  __syncthreads();
  if (threadIdx.x == 0) {
    __hip_atomic_fetch_add(bar, 1u, __ATOMIC_RELEASE, __HIP_MEMORY_SCOPE_AGENT);
    while (__hip_atomic_load(bar, __ATOMIC_ACQUIRE, __HIP_MEMORY_SCOPE_AGENT) < target) {
      __builtin_amdgcn_s_sleep(2);
    }
  }
  __syncthreads();
}

// ---------------------------------------------------------------------------
// rnn_fused: 64 RNN steps + FC1 + FC2 in ONE dispatch (grid 256 x 256thr).
// Replaces 66 serial launches (~10us launch overhead each = the round-2
// bottleneck). Barrier counter = ws bytes 0..3 (emb PAD row, zeroed by prep,
// dead after xproj).
// ---------------------------------------------------------------------------
__global__ __launch_bounds__(256) void rnn_fused_kernel(
    const float* __restrict__ b_hh, const float* __restrict__ fc1_b,
    const float* __restrict__ fc2_b, const int* __restrict__ lens,
    char* __restrict__ ws, float* __restrict__ out) {
  __shared__ bf16 Asm[2][32][128];  // 16 KB
  __shared__ bf16 Bsm[2][64][128];  // 32 KB

  unsigned* bar = (unsigned*)(ws + EMB_OFF);
  const bf16* whh = (const bf16*)(ws + WHH_OFF);
  const bf16* fc1 = (const bf16*)(ws + FC1_OFF);
  const bf16* fc2 = (const bf16*)(ws + FC2_OFF);
  const bf16* xp  = (const bf16*)(ws + XP_OFF);
  bf16* hb0 = (bf16*)(ws + H0_OFF);
  bf16* hb1 = (bf16*)(ws + H1_OFF);
  bf16* yl  = (bf16*)(ws + YL_OFF);
  bf16* y1  = (bf16*)(ws + Y1_OFF);

  const int tid = threadIdx.x;
  const int mb = blockIdx.x >> 4;  // 0..15
  const int nb = blockIdx.x & 15;  // 0..15
  const int rowBase = mb * 32;
  const int colBase = nb * 64;

  unsigned ep = 0;
  for (int t = 0; t < S_SZ; ++t) {
    const bf16* hin = (t & 1) ? hb1 : hb0;
    bf16* ho = (t & 1) ? hb0 : hb1;
    gemm_tile<0>(hin, whh, b_hh, xp + (size_t)t * (B_SZ * H_SZ), lens, t,
                 ho, yl, nullptr, Asm, Bsm, tid, rowBase, colBase);
    ++ep;
    gridbar(bar, ep * 256u);
  }

  gemm_tile<1>(yl, fc1, fc1_b, nullptr, nullptr, 0, y1, nullptr, nullptr,
               Asm, Bsm, tid, rowBase, colBase);
  ++ep;
  gridbar(bar, ep * 256u);

  gemm_tile<2>(y1, fc2, fc2_b, nullptr, nullptr, 0, nullptr, nullptr, out,
               Asm, Bsm, tid, rowBase, colBase);
}

// ---------------------------------------------------------------------------
extern "C" void kernel_launch(void* const* d_in, const int* in_sizes, int n_in,
                              void* d_out, int out_size, void* d_ws, size_t ws_size,
                              hipStream_t stream) {
  (void)in_sizes; (void)n_in; (void)out_size; (void)ws_size;
  const int* x_in = (const int*)d_in[0];
  const int* x_len = (const int*)d_in[1];
  const float* emb_w = (const float*)d_in[2];
  const float* w_ih = (const float*)d_in[3];
  const float* b_ih = (const float*)d_in[4];
  const float* w_hh = (const float*)d_in[5];
  const float* b_hh = (const float*)d_in[6];
  const float* fc1_w = (const float*)d_in[7];
  const float* fc1_b = (const float*)d_in[8];
  const float* fc2_w = (const float*)d_in[9];
  const float* fc2_b = (const float*)d_in[10];
  char* ws = (char*)d_ws;
  float* out = (float*)d_out;

  // 1) weights -> bf16, zero h0, pad fc2, zero barrier bytes (emb row 0)
  prep_kernel<<<2048, 256, 0, stream>>>(emb_w, w_ih, w_hh, fc1_w, fc2_w, ws);

  // 2) x_proj GEMM (gathered A), [S*B, H]
  xproj_kernel<<<2048, 256, 0, stream>>>(x_in, b_ih, ws);

  // 3) fused: 64 RNN steps + FC1 + FC2, single dispatch with grid barrier
  rnn_fused_kernel<<<256, 256, 0, stream>>>(b_hh, fc1_b, fc2_b, x_len, ws, out);
}

// Round 6
// 1264.886 us; speedup vs baseline: 1.2480x; 1.2480x over previous
//
#include <hip/hip_runtime.h>
#include <hip/hip_bf16.h>
#include <stdint.h>
#include <stddef.h>

// Problem sizes (fixed by the reference)
#define B_SZ 512
#define S_SZ 64
#define E_SZ 512
#define H_SZ 1024
#define V_SZ 1024
#define C_SZ 1000

typedef __hip_bfloat16 bf16;
typedef __attribute__((ext_vector_type(8))) __bf16 bf16x8;
typedef __attribute__((ext_vector_type(4))) float f32x4;

// ---- workspace layout (bytes), total 76 MB ----
#define EMB_OFF   (0ull)          // emb_w bf16    [1024][512]  1 MB (dead after xproj)
#define WIH_OFF   (1ull << 20)    // w_ih  bf16    [1024][512]  1 MB
#define WHH_OFF   (2ull << 20)    // w_hh  bf16    [1024][1024] 2 MB
#define FC1_OFF   (4ull << 20)    // fc1_w bf16    [1024][1024] 2 MB
#define FC2_OFF   (6ull << 20)    // fc2_w bf16    [1024][1024] 2 MB (rows >=1000 zero)
#define H0_OFF    (8ull << 20)    // h buf 0 bf16  [512][1024]  1 MB
#define H1_OFF    (9ull << 20)    // h buf 1 bf16  [512][1024]  1 MB
#define YL_OFF    (10ull << 20)   // y_last bf16   [512][1024]  1 MB
#define Y1_OFF    (11ull << 20)   // fc1 out bf16  [512][1024]  1 MB
#define XP_OFF    (12ull << 20)   // x_proj bf16   [64][512][1024] 64 MB
// 16 cluster-barrier counters, 128B apart, inside fc2's zero-padded rows
// (rows 1000..1023: prep-zeroed; only ever READ as B-weights for output
// cols >=1000, which are discarded -> counter values there are harmless).
#define BAR_OFF   (FC2_OFF + 2048000ull)   // = row 1000 of fc2, 128B-aligned

// async global->LDS, 16B/lane. HW writes lane l at lds_base + l*16 (linear,
// wave-uniform base). Swizzled layouts: pre-swizzle the per-lane GLOBAL source
// chunk (rule #21: linear dest + inv-swz source + swz on read; XOR self-inverse).
__device__ __forceinline__ void gl_lds16(const void* g, void* l) {
  __builtin_amdgcn_global_load_lds(
      (const __attribute__((address_space(1))) unsigned int*)g,
      (__attribute__((address_space(3))) unsigned int*)l, 16, 0, 0);
}

// ---------------------------------------------------------------------------
// prep: fp32 -> bf16 weight conversion + zero-init h0 + zero-pad fc2 rows.
// Forces emb row 0 to exact zeros (PAD row). fc2 pad rows (incl. barrier
// counters at BAR_OFF) are zeroed here.
// ---------------------------------------------------------------------------
__global__ __launch_bounds__(256) void prep_kernel(
    const float* __restrict__ emb_w, const float* __restrict__ w_ih,
    const float* __restrict__ w_hh, const float* __restrict__ fc1_w,
    const float* __restrict__ fc2_w, char* __restrict__ ws) {
  bf16* emb = (bf16*)(ws + EMB_OFF);
  bf16* wih = (bf16*)(ws + WIH_OFF);
  bf16* whh = (bf16*)(ws + WHH_OFF);
  bf16* fc1 = (bf16*)(ws + FC1_OFF);
  bf16* fc2 = (bf16*)(ws + FC2_OFF);
  bf16* h0  = (bf16*)(ws + H0_OFF);

  const long N_EMB = 524288;   // 1024*512
  const long N_WIH = 524288;
  const long N_WHH = 1048576;  // 1024*1024
  const long N_FC1 = 1048576;
  const long N_FC2 = 1048576;  // padded to 1024 rows
  const long N_H0  = 524288;   // 512*1024
  const long TOTAL = N_EMB + N_WIH + N_WHH + N_FC1 + N_FC2 + N_H0;

  long stride = (long)gridDim.x * blockDim.x;
  for (long i = (long)blockIdx.x * blockDim.x + threadIdx.x; i < TOTAL; i += stride) {
    long j = i;
    if (j < N_EMB) {
      // row 0 forced to zero (PAD row per reference)
      emb[j] = (j < E_SZ) ? __float2bfloat16(0.f) : __float2bfloat16(emb_w[j]);
      continue;
    }
    j -= N_EMB;
    if (j < N_WIH) { wih[j] = __float2bfloat16(w_ih[j]); continue; }
    j -= N_WIH;
    if (j < N_WHH) { whh[j] = __float2bfloat16(w_hh[j]); continue; }
    j -= N_WHH;
    if (j < N_FC1) { fc1[j] = __float2bfloat16(fc1_w[j]); continue; }
    j -= N_FC1;
    if (j < N_FC2) {
      // rows >= 1000 zeroed: pad weights AND the cluster-barrier counters
      fc2[j] = (j < (long)C_SZ * H_SZ) ? __float2bfloat16(fc2_w[j]) : __float2bfloat16(0.f);
      continue;
    }
    j -= N_FC2;
    h0[j] = __float2bfloat16(0.f);
  }
}

// ---------------------------------------------------------------------------
// xproj: xp[s][b][h] = sum_e emb[x_in[b][s]][e] * w_ih[h][e] + b_ih[h]
// GEMM M=32768 (r=s*512+b), N=1024, K=512. Tile 128x128, BK=64, 4 waves,
// double-buffered + XOR-swizzled LDS, gather folded into staging addresses.
// (round 2: 46.6 us, bank conflicts = 0, passed — unchanged)
// ---------------------------------------------------------------------------
__global__ __launch_bounds__(256) void xproj_kernel(
    const int* __restrict__ x_in, const float* __restrict__ b_ih,
    char* __restrict__ ws) {
  const bf16* emb = (const bf16*)(ws + EMB_OFF);
  const bf16* wih = (const bf16*)(ws + WIH_OFF);
  bf16* xp = (bf16*)(ws + XP_OFF);

  __shared__ bf16 Asm[2][128][64];  // 16 KB per buffer
  __shared__ bf16 Bsm[2][128][64];

  const int tid = threadIdx.x;
  const int lane = tid & 63;
  const int wid = tid >> 6;
  const int mb = blockIdx.x >> 3;  // 0..255
  const int nb = blockIdx.x & 7;   // 0..7
  const int rowBase = mb * 128;
  const int colBase = nb * 128;
  const int s = rowBase >> 9;      // whole 128-row tile shares one s

  const int lrow = lane >> 3;      // 0..7
  const int lchk = lane & 7;       // 0..7 (8-bf16 chunks)

  int tok[4];
#pragma unroll
  for (int i = 0; i < 4; ++i) {
    int rt = wid * 32 + i * 8 + lrow;
    int b = (rowBase + rt) & 511;
    tok[i] = x_in[b * S_SZ + s];
  }

  const int wr = wid >> 1, wc = wid & 1;
  f32x4 acc[4][4];
#pragma unroll
  for (int i = 0; i < 4; ++i)
#pragma unroll
    for (int j = 0; j < 4; ++j) acc[i][j] = (f32x4){0.f, 0.f, 0.f, 0.f};

  auto stage = [&](int buf, int k0) {
#pragma unroll
    for (int i = 0; i < 4; ++i) {
      int rt = wid * 32 + i * 8;                      // wave-uniform
      int sc = (lchk ^ ((rt + lrow) & 7)) * 8;        // inv-swizzled source
      gl_lds16(emb + (size_t)tok[i] * E_SZ + k0 + sc, &Asm[buf][rt][0]);
    }
#pragma unroll
    for (int i = 0; i < 4; ++i) {
      int rt = wid * 32 + i * 8;
      int sc = (lchk ^ ((rt + lrow) & 7)) * 8;
      gl_lds16(wih + (size_t)(colBase + rt + lrow) * E_SZ + k0 + sc, &Bsm[buf][rt][0]);
    }
  };

  stage(0, 0);
  __syncthreads();
  int cur = 0;
  for (int t8 = 0; t8 < 8; ++t8) {   // K = 8 * 64
    if (t8 < 7) stage(cur ^ 1, (t8 + 1) * 64);
#pragma unroll
    for (int kk = 0; kk < 2; ++kk) {
      const int kfc = kk * 4 + (lane >> 4);  // chunk index 0..7
      bf16x8 a[4], b[4];
#pragma unroll
      for (int i = 0; i < 4; ++i) {
        int r = wr * 64 + i * 16 + (lane & 15);
        a[i] = *(const bf16x8*)&Asm[cur][r][(kfc ^ (r & 7)) * 8];
      }
#pragma unroll
      for (int j = 0; j < 4; ++j) {
        int r = wc * 64 + j * 16 + (lane & 15);
        b[j] = *(const bf16x8*)&Bsm[cur][r][(kfc ^ (r & 7)) * 8];
      }
#pragma unroll
      for (int i = 0; i < 4; ++i)
#pragma unroll
        for (int j = 0; j < 4; ++j)
          acc[i][j] = __builtin_amdgcn_mfma_f32_16x16x32_bf16(a[i], b[j], acc[i][j], 0, 0, 0);
    }
    __syncthreads();  // implicit vmcnt(0)+lgkmcnt(0): dbuf safe w/ 1 barrier
    cur ^= 1;
  }

  const int crow = (lane >> 4) * 4;
  const int ccol = lane & 15;
#pragma unroll
  for (int j = 0; j < 4; ++j) {
    const int col = colBase + wc * 64 + j * 16 + ccol;
    const float bias = b_ih[col];
#pragma unroll
    for (int i = 0; i < 4; ++i) {
      const int r0 = rowBase + wr * 64 + i * 16 + crow;
#pragma unroll
      for (int reg = 0; reg < 4; ++reg) {
        float v = acc[i][j][reg] + bias;
        xp[(size_t)(r0 + reg) * H_SZ + col] = __float2bfloat16(v);
      }
    }
  }
}

// ---------------------------------------------------------------------------
// gemm_tile: one 32x64 output tile, K=1024, BK=128, 4 waves (2x2 of 16x32),
// double-buffered + XOR-swizzled LDS. Exact math from round-2's gemm32
// (passed).
// MODE 0: h_out = tanh(A@B^T + xp_t + bias); capture y_last at t==len-1
// MODE 1: out = relu(A@B^T + bias) -> bf16
// MODE 2: out = A@B^T + bias -> fp32 (cols < 1000)
// ---------------------------------------------------------------------------
template <int MODE>
__device__ __forceinline__ void gemm_tile(
    const bf16* __restrict__ A, const bf16* __restrict__ Bw,
    const float* __restrict__ bias, const bf16* __restrict__ xp_t,
    const int* __restrict__ lens, int t,
    bf16* __restrict__ hout, bf16* __restrict__ yl, float* __restrict__ out_f32,
    bf16 (&Asm)[2][32][128], bf16 (&Bsm)[2][64][128],
    int tid, int rowBase, int colBase) {
  const int lane = tid & 63;
  const int wid = tid >> 6;
  const int wr = wid >> 1, wc = wid & 1;

  const int lrow = lane >> 4;      // 0..3
  const int lchk = lane & 15;      // 0..15 (8-bf16 chunks)

  f32x4 acc[2];
#pragma unroll
  for (int j = 0; j < 2; ++j) acc[j] = (f32x4){0.f, 0.f, 0.f, 0.f};

  auto stage = [&](int buf, int k0) {
#pragma unroll
    for (int i = 0; i < 2; ++i) {                      // A: 8 rows per wave
      int rt = wid * 8 + i * 4;                        // wave-uniform
      int sc = (lchk ^ ((rt + lrow) & 7)) * 8;         // inv-swizzled source
      gl_lds16(A + (size_t)(rowBase + rt + lrow) * H_SZ + k0 + sc, &Asm[buf][rt][0]);
    }
#pragma unroll
    for (int i = 0; i < 4; ++i) {                      // B: 16 rows per wave
      int rt = wid * 16 + i * 4;
      int sc = (lchk ^ ((rt + lrow) & 7)) * 8;
      gl_lds16(Bw + (size_t)(colBase + rt + lrow) * H_SZ + k0 + sc, &Bsm[buf][rt][0]);
    }
  };

  stage(0, 0);
  __syncthreads();
  int cur = 0;
  for (int t8 = 0; t8 < 8; ++t8) {   // K = 8 * 128
    if (t8 < 7) stage(cur ^ 1, (t8 + 1) * 128);
#pragma unroll
    for (int kc = 0; kc < 4; ++kc) {
      const int kfc = kc * 4 + (lane >> 4);  // chunk index 0..15
      const int ra = wr * 16 + (lane & 15);
      bf16x8 a = *(const bf16x8*)&Asm[cur][ra][(kfc ^ (ra & 7)) * 8];
#pragma unroll
      for (int j = 0; j < 2; ++j) {
        const int rb = wc * 32 + j * 16 + (lane & 15);
        bf16x8 b = *(const bf16x8*)&Bsm[cur][rb][(kfc ^ (rb & 7)) * 8];
        acc[j] = __builtin_amdgcn_mfma_f32_16x16x32_bf16(a, b, acc[j], 0, 0, 0);
      }
    }
    __syncthreads();
    cur ^= 1;
  }

  const int crow = (lane >> 4) * 4;
  const int ccol = lane & 15;
#pragma unroll
  for (int j = 0; j < 2; ++j) {
    const int col = colBase + wc * 32 + j * 16 + ccol;
    const float bv = (MODE == 2 && col >= C_SZ) ? 0.f : bias[col];
#pragma unroll
    for (int reg = 0; reg < 4; ++reg) {
      const int row = rowBase + wr * 16 + crow + reg;
      float v = acc[j][reg] + bv;
      if (MODE == 0) {
        v += __bfloat162float(xp_t[(size_t)row * H_SZ + col]);
        float h = tanhf(v);
        bf16 hb = __float2bfloat16(h);
        hout[(size_t)row * H_SZ + col] = hb;
        if (t == lens[row] - 1) yl[(size_t)row * H_SZ + col] = hb;
      } else if (MODE == 1) {
        v = fmaxf(v, 0.f);
        hout[(size_t)row * H_SZ + col] = __float2bfloat16(v);
      } else {
        if (col < C_SZ) out_f32[(size_t)row * C_SZ + col] = v;
      }
    }
  }
}

// ---------------------------------------------------------------------------
// CLUSTER barrier (fan-in 16). Key insight: the RNN recurrence is per-batch-
// row — WG(mb,nb) reads only h rows [mb*32, mb*32+32), written exclusively by
// the 16 WGs sharing mb. Same row-locality holds for yl->FC1 and y1->FC2.
// So a 16-WG barrier per row-cluster replaces the 256-WG global barrier.
// Spin uses RELAXED agent loads (no per-poll cache invalidate — round-4's
// 23us/step bug); periodic ACQUIRE as progress safety net; one ACQUIRE at
// exit publishes peer h-stores (writers did RELEASE on the add).
// Co-residency: 48KB LDS -> 3 WG/CU capacity, grid 256 <= 256 CUs -> safe.
// ---------------------------------------------------------------------------
__device__ __forceinline__ void clusterbar(unsigned* bar, unsigned target) {
  __syncthreads();
  if (threadIdx.x == 0) {
    __hip_atomic_fetch_add(bar, 1u, __ATOMIC_RELEASE, __HIP_MEMORY_SCOPE_AGENT);
    unsigned k = 0;
    while (__hip_atomic_load(bar, __ATOMIC_RELAXED, __HIP_MEMORY_SCOPE_AGENT) < target) {
      if ((++k & 31u) == 0u)
        (void)__hip_atomic_load(bar, __ATOMIC_ACQUIRE, __HIP_MEMORY_SCOPE_AGENT);
      __builtin_amdgcn_s_sleep(1);
    }
    (void)__hip_atomic_load(bar, __ATOMIC_ACQUIRE, __HIP_MEMORY_SCOPE_AGENT);
  }
  __syncthreads();
}

// ---------------------------------------------------------------------------
// rnn_fused: 64 RNN steps + FC1 + FC2 in ONE dispatch (grid 256 x 256thr).
// Sync = per-cluster (mb) barrier, fan-in 16, counters in fc2 pad rows.
// ---------------------------------------------------------------------------
__global__ __launch_bounds__(256) void rnn_fused_kernel(
    const float* __restrict__ b_hh, const float* __restrict__ fc1_b,
    const float* __restrict__ fc2_b, const int* __restrict__ lens,
    char* __restrict__ ws, float* __restrict__ out) {
  __shared__ bf16 Asm[2][32][128];  // 16 KB
  __shared__ bf16 Bsm[2][64][128];  // 32 KB

  const bf16* whh = (const bf16*)(ws + WHH_OFF);
  const bf16* fc1 = (const bf16*)(ws + FC1_OFF);
  const bf16* fc2 = (const bf16*)(ws + FC2_OFF);
  const bf16* xp  = (const bf16*)(ws + XP_OFF);
  bf16* hb0 = (bf16*)(ws + H0_OFF);
  bf16* hb1 = (bf16*)(ws + H1_OFF);
  bf16* yl  = (bf16*)(ws + YL_OFF);
  bf16* y1  = (bf16*)(ws + Y1_OFF);

  const int tid = threadIdx.x;
  const int mb = blockIdx.x >> 4;  // 0..15  (row-cluster id)
  const int nb = blockIdx.x & 15;  // 0..15
  const int rowBase = mb * 32;
  const int colBase = nb * 64;

  unsigned* bar = (unsigned*)(ws + BAR_OFF + (size_t)mb * 128);

  unsigned ep = 0;
  for (int t = 0; t < S_SZ; ++t) {
    const bf16* hin = (t & 1) ? hb1 : hb0;
    bf16* ho = (t & 1) ? hb0 : hb1;
    gemm_tile<0>(hin, whh, b_hh, xp + (size_t)t * (B_SZ * H_SZ), lens, t,
                 ho, yl, nullptr, Asm, Bsm, tid, rowBase, colBase);
    ++ep;
    clusterbar(bar, ep * 16u);
  }

  gemm_tile<1>(yl, fc1, fc1_b, nullptr, nullptr, 0, y1, nullptr, nullptr,
               Asm, Bsm, tid, rowBase, colBase);
  ++ep;
  clusterbar(bar, ep * 16u);

  gemm_tile<2>(y1, fc2, fc2_b, nullptr, nullptr, 0, nullptr, nullptr, out,
               Asm, Bsm, tid, rowBase, colBase);
}

// ---------------------------------------------------------------------------
extern "C" void kernel_launch(void* const* d_in, const int* in_sizes, int n_in,
                              void* d_out, int out_size, void* d_ws, size_t ws_size,
                              hipStream_t stream) {
  (void)in_sizes; (void)n_in; (void)out_size; (void)ws_size;
  const int* x_in = (const int*)d_in[0];
  const int* x_len = (const int*)d_in[1];
  const float* emb_w = (const float*)d_in[2];
  const float* w_ih = (const float*)d_in[3];
  const float* b_ih = (const float*)d_in[4];
  const float* w_hh = (const float*)d_in[5];
  const float* b_hh = (const float*)d_in[6];
  const float* fc1_w = (const float*)d_in[7];
  const float* fc1_b = (const float*)d_in[8];
  const float* fc2_w = (const float*)d_in[9];
  const float* fc2_b = (const float*)d_in[10];
  char* ws = (char*)d_ws;
  float* out = (float*)d_out;

  // 1) weights -> bf16, zero h0, pad fc2 (incl. barrier counters)
  prep_kernel<<<2048, 256, 0, stream>>>(emb_w, w_ih, w_hh, fc1_w, fc2_w, ws);

  // 2) x_proj GEMM (gathered A), [S*B, H]
  xproj_kernel<<<2048, 256, 0, stream>>>(x_in, b_ih, ws);

  // 3) fused: 64 RNN steps + FC1 + FC2, single dispatch, cluster barriers
  rnn_fused_kernel<<<256, 256, 0, stream>>>(b_hh, fc1_b, fc2_b, x_len, ws, out);
}

// Round 7
// 737.531 us; speedup vs baseline: 2.1404x; 1.7150x over previous
//
#include <hip/hip_runtime.h>
#include <hip/hip_bf16.h>
#include <stdint.h>
#include <stddef.h>

// Problem sizes (fixed by the reference)
#define B_SZ 512
#define S_SZ 64
#define E_SZ 512
#define H_SZ 1024
#define V_SZ 1024
#define C_SZ 1000

typedef __hip_bfloat16 bf16;
typedef __attribute__((ext_vector_type(8))) __bf16 bf16x8;
typedef __attribute__((ext_vector_type(4))) float f32x4;

// ---- workspace layout (bytes), total 76 MB (same proven bound) ----
#define EMB_OFF   (0ull)          // emb bf16 [1024][512] (xproj input); REUSED as yl [512][1024] by fused
#define WIH_OFF   (1ull << 20)    // w_ih bf16 (xproj input); REUSED as y1 by fused
#define WHH_OFF   (2ull << 20)    // w_hh  bf16 [1024][1024] 2 MB
#define FC1_OFF   (4ull << 20)    // fc1_w bf16 [1024][1024] 2 MB
#define FC2_OFF   (6ull << 20)    // fc2_w bf16 [1024][1024] 2 MB (rows >=1000 zero)
#define HB_OFF    (8ull << 20)    // 4 rotating h bufs, 1 MB each; buf0 zeroed by prep
#define XP_OFF    (12ull << 20)   // x_proj bf16 [64][512][1024] 64 MB
// 16 cluster counters, 128B apart, in fc2 zero-pad rows (read only as discarded-col weights)
#define BAR_OFF   (FC2_OFF + 2048000ull)

// async global->LDS, 16B/lane; lane l lands at lds_base + l*16 (linear).
__device__ __forceinline__ void gl_lds16(const void* g, void* l) {
  __builtin_amdgcn_global_load_lds(
      (const __attribute__((address_space(1))) unsigned int*)g,
      (__attribute__((address_space(3))) unsigned int*)l, 16, 0, 0);
}

// ---------------------------------------------------------------------------
// prep: fp32 -> bf16 weights + zero h_buf0 + zero fc2 pad rows (incl counters)
// ---------------------------------------------------------------------------
__global__ __launch_bounds__(256) void prep_kernel(
    const float* __restrict__ emb_w, const float* __restrict__ w_ih,
    const float* __restrict__ w_hh, const float* __restrict__ fc1_w,
    const float* __restrict__ fc2_w, char* __restrict__ ws) {
  bf16* emb = (bf16*)(ws + EMB_OFF);
  bf16* wih = (bf16*)(ws + WIH_OFF);
  bf16* whh = (bf16*)(ws + WHH_OFF);
  bf16* fc1 = (bf16*)(ws + FC1_OFF);
  bf16* fc2 = (bf16*)(ws + FC2_OFF);
  bf16* h0  = (bf16*)(ws + HB_OFF);

  const long N_EMB = 524288, N_WIH = 524288, N_WHH = 1048576;
  const long N_FC1 = 1048576, N_FC2 = 1048576, N_H0 = 524288;
  const long TOTAL = N_EMB + N_WIH + N_WHH + N_FC1 + N_FC2 + N_H0;

  long stride = (long)gridDim.x * blockDim.x;
  for (long i = (long)blockIdx.x * blockDim.x + threadIdx.x; i < TOTAL; i += stride) {
    long j = i;
    if (j < N_EMB) {  // row 0 forced zero (PAD row)
      emb[j] = (j < E_SZ) ? __float2bfloat16(0.f) : __float2bfloat16(emb_w[j]);
      continue;
    }
    j -= N_EMB;
    if (j < N_WIH) { wih[j] = __float2bfloat16(w_ih[j]); continue; }
    j -= N_WIH;
    if (j < N_WHH) { whh[j] = __float2bfloat16(w_hh[j]); continue; }
    j -= N_WHH;
    if (j < N_FC1) { fc1[j] = __float2bfloat16(fc1_w[j]); continue; }
    j -= N_FC1;
    if (j < N_FC2) {
      fc2[j] = (j < (long)C_SZ * H_SZ) ? __float2bfloat16(fc2_w[j]) : __float2bfloat16(0.f);
      continue;
    }
    j -= N_FC2;
    h0[j] = __float2bfloat16(0.f);
  }
}

// ---------------------------------------------------------------------------
// xproj (unchanged, proven: 46.6us, 0 bank conflicts)
// ---------------------------------------------------------------------------
__global__ __launch_bounds__(256) void xproj_kernel(
    const int* __restrict__ x_in, const float* __restrict__ b_ih,
    char* __restrict__ ws) {
  const bf16* emb = (const bf16*)(ws + EMB_OFF);
  const bf16* wih = (const bf16*)(ws + WIH_OFF);
  bf16* xp = (bf16*)(ws + XP_OFF);

  __shared__ bf16 Asm[2][128][64];
  __shared__ bf16 Bsm[2][128][64];

  const int tid = threadIdx.x;
  const int lane = tid & 63;
  const int wid = tid >> 6;
  const int mb = blockIdx.x >> 3;
  const int nb = blockIdx.x & 7;
  const int rowBase = mb * 128;
  const int colBase = nb * 128;
  const int s = rowBase >> 9;

  const int lrow = lane >> 3;
  const int lchk = lane & 7;

  int tok[4];
#pragma unroll
  for (int i = 0; i < 4; ++i) {
    int rt = wid * 32 + i * 8 + lrow;
    int b = (rowBase + rt) & 511;
    tok[i] = x_in[b * S_SZ + s];
  }

  const int wr = wid >> 1, wc = wid & 1;
  f32x4 acc[4][4];
#pragma unroll
  for (int i = 0; i < 4; ++i)
#pragma unroll
    for (int j = 0; j < 4; ++j) acc[i][j] = (f32x4){0.f, 0.f, 0.f, 0.f};

  auto stage = [&](int buf, int k0) {
#pragma unroll
    for (int i = 0; i < 4; ++i) {
      int rt = wid * 32 + i * 8;
      int sc = (lchk ^ ((rt + lrow) & 7)) * 8;
      gl_lds16(emb + (size_t)tok[i] * E_SZ + k0 + sc, &Asm[buf][rt][0]);
    }
#pragma unroll
    for (int i = 0; i < 4; ++i) {
      int rt = wid * 32 + i * 8;
      int sc = (lchk ^ ((rt + lrow) & 7)) * 8;
      gl_lds16(wih + (size_t)(colBase + rt + lrow) * E_SZ + k0 + sc, &Bsm[buf][rt][0]);
    }
  };

  stage(0, 0);
  __syncthreads();
  int cur = 0;
  for (int t8 = 0; t8 < 8; ++t8) {
    if (t8 < 7) stage(cur ^ 1, (t8 + 1) * 64);
#pragma unroll
    for (int kk = 0; kk < 2; ++kk) {
      const int kfc = kk * 4 + (lane >> 4);
      bf16x8 a[4], b[4];
#pragma unroll
      for (int i = 0; i < 4; ++i) {
        int r = wr * 64 + i * 16 + (lane & 15);
        a[i] = *(const bf16x8*)&Asm[cur][r][(kfc ^ (r & 7)) * 8];
      }
#pragma unroll
      for (int j = 0; j < 4; ++j) {
        int r = wc * 64 + j * 16 + (lane & 15);
        b[j] = *(const bf16x8*)&Bsm[cur][r][(kfc ^ (r & 7)) * 8];
      }
#pragma unroll
      for (int i = 0; i < 4; ++i)
#pragma unroll
        for (int j = 0; j < 4; ++j)
          acc[i][j] = __builtin_amdgcn_mfma_f32_16x16x32_bf16(a[i], b[j], acc[i][j], 0, 0, 0);
    }
    __syncthreads();
    cur ^= 1;
  }

  const int crow = (lane >> 4) * 4;
  const int ccol = lane & 15;
#pragma unroll
  for (int j = 0; j < 4; ++j) {
    const int col = colBase + wc * 64 + j * 16 + ccol;
    const float bias = b_ih[col];
#pragma unroll
    for (int i = 0; i < 4; ++i) {
      const int r0 = rowBase + wr * 64 + i * 16 + crow;
#pragma unroll
      for (int reg = 0; reg < 4; ++reg) {
        float v = acc[i][j][reg] + bias;
        xp[(size_t)(r0 + reg) * H_SZ + col] = __float2bfloat16(v);
      }
    }
  }
}

// ---------------------------------------------------------------------------
// fused-kernel staging helpers. LDS tiles use 64-elem (128B) rows + XOR
// swizzle — the xproj-proven zero-conflict shape.
// ---------------------------------------------------------------------------
// A pipe: one op per wave covers 8 rows x 64 K (1KB). lds[r][c] = global chunk c^r.
__device__ __forceinline__ void stage_rowsA(const bf16* src, bf16* ApBuf,
                                            int lane, int wid, int rowBase, int k0) {
  const int r = lane >> 3, c = lane & 7;
  const bf16* g = src + (size_t)(rowBase + wid * 8 + r) * H_SZ + k0 + ((c ^ r) << 3);
  gl_lds16(g, ApBuf + wid * 512);
}

// pinned B: [64][1024] bf16 = 128KB. 128 ops (row, half), 32 per wave.
// lds[r][hf*64 + l] = global chunk hf*64 + (l ^ (r&7)).
__device__ __forceinline__ void stage_pinB(const bf16* w, bf16* Bsm,
                                           int lane, int wid, int colBase) {
#pragma unroll
  for (int oo = 0; oo < 32; ++oo) {
    const int o = wid * 32 + oo;
    const int r = o >> 1, hf = o & 1;
    const bf16* g = w + (size_t)(colBase + r) * H_SZ + hf * 512 + ((lane ^ (r & 7)) << 3);
    gl_lds16(g, Bsm + r * H_SZ + hf * 512);
  }
}

// ---------------------------------------------------------------------------
// Cluster barrier (fan-in 16). RELEASE add publishes h (wbl2); RELAXED agent
// polls are MALL-serviced (no invalidates). `acq` (every 4th step + FC
// boundaries) does ONE acquire-invalidate — needed only when an h-buffer
// address is about to be REUSED (4-step rotation; see schedule proof at call
// site). Compiler memory clobber + __syncthreads order subsequent reads.
// ---------------------------------------------------------------------------
__device__ __forceinline__ void clusterbar(unsigned* bar, unsigned target, bool acq) {
  __syncthreads();
  if (threadIdx.x == 0) {
    __hip_atomic_fetch_add(bar, 1u, __ATOMIC_RELEASE, __HIP_MEMORY_SCOPE_AGENT);
    while (__hip_atomic_load(bar, __ATOMIC_RELAXED, __HIP_MEMORY_SCOPE_AGENT) < target)
      __builtin_amdgcn_s_sleep(1);
    if (acq)
      (void)__hip_atomic_load(bar, __ATOMIC_ACQUIRE, __HIP_MEMORY_SCOPE_AGENT);
  }
  asm volatile("" ::: "memory");
  __syncthreads();
}

// ---------------------------------------------------------------------------
// phase: one 32x64 output tile vs pinned-B, K=1024, counted-vmcnt 4-deep
// A pipeline (BK=64). MODE 0: RNN step; 1: FC1 relu; 2: FC2 fp32 out.
// vmcnt math: stages retire in order; at iter i, >=2 stage ops are issued
// after s_i, so vmcnt(2) guarantees s_i complete (vmcnt(1)/(0) at i=14/15).
// Stage for buf (i+3) is issued AFTER the barrier -> cannot overwrite buf
// (i-1) while any wave still reads it.
// ---------------------------------------------------------------------------
template <int MODE>
__device__ __forceinline__ void phase(
    const bf16* __restrict__ Asrc, const bf16* Bsm, bf16* Ap,
    int lane, int wid, int rowBase, int colBase,
    const float* __restrict__ bias, const bf16* __restrict__ xpt,
    const int* __restrict__ lens, int t,
    bf16* __restrict__ dst_bf, bf16* __restrict__ yl,
    float* __restrict__ outf) {
  const int wr = wid >> 1, wc = wid & 1;
  const int r0 = rowBase + wr * 16 + (lane >> 4) * 4;
  const int c0 = colBase + wc * 32 + (lane & 15);
  const int sw = lane & 7;

  f32x4 acc[2];
  acc[0] = (f32x4){0.f, 0.f, 0.f, 0.f};
  acc[1] = (f32x4){0.f, 0.f, 0.f, 0.f};

  bf16 xv[2][4];
  if constexpr (MODE == 0) {
#pragma unroll
    for (int j = 0; j < 2; ++j)
#pragma unroll
      for (int reg = 0; reg < 4; ++reg)
        xv[j][reg] = xpt[(size_t)(r0 + reg) * H_SZ + c0 + j * 16];
  }

  // prologue: 3 bufs in flight (clobbers pin the issue order s0<s1<s2)
  stage_rowsA(Asrc, Ap + 0 * 2048, lane, wid, rowBase, 0);
  asm volatile("" ::: "memory");
  stage_rowsA(Asrc, Ap + 1 * 2048, lane, wid, rowBase, 64);
  asm volatile("" ::: "memory");
  stage_rowsA(Asrc, Ap + 2 * 2048, lane, wid, rowBase, 128);

#pragma unroll
  for (int i = 0; i < 16; ++i) {
    if (i < 14)       asm volatile("s_waitcnt vmcnt(2)" ::: "memory");
    else if (i == 14) asm volatile("s_waitcnt vmcnt(1)" ::: "memory");
    else              asm volatile("s_waitcnt vmcnt(0)" ::: "memory");
    __builtin_amdgcn_s_barrier();
    asm volatile("" ::: "memory");
    if (i < 13)
      stage_rowsA(Asrc, Ap + ((i + 3) & 3) * 2048, lane, wid, rowBase, (i + 3) * 64);
    const bf16* Ab = Ap + (i & 3) * 2048;
#pragma unroll
    for (int kk = 0; kk < 2; ++kk) {
      const int kfc = kk * 4 + (lane >> 4);
      const int ra = wr * 16 + (lane & 15);
      bf16x8 a = *(const bf16x8*)(Ab + ra * 64 + ((kfc ^ sw) << 3));
      const int rb0 = wc * 32 + (lane & 15);
      bf16x8 b0 = *(const bf16x8*)(Bsm + rb0 * H_SZ + ((i * 8 + (kfc ^ sw)) << 3));
      bf16x8 b1 = *(const bf16x8*)(Bsm + (rb0 + 16) * H_SZ + ((i * 8 + (kfc ^ sw)) << 3));
      acc[0] = __builtin_amdgcn_mfma_f32_16x16x32_bf16(a, b0, acc[0], 0, 0, 0);
      acc[1] = __builtin_amdgcn_mfma_f32_16x16x32_bf16(a, b1, acc[1], 0, 0, 0);
    }
  }

  // epilogue (D map: col=lane&15, row=(lane>>4)*4+reg — m89-verified)
#pragma unroll
  for (int j = 0; j < 2; ++j) {
    const int col = c0 + j * 16;
#pragma unroll
    for (int reg = 0; reg < 4; ++reg) {
      const int row = r0 + reg;
      float v = acc[j][reg];
      if constexpr (MODE == 0) {
        v += bias[col] + __bfloat162float(xv[j][reg]);
        v = fminf(fmaxf(v, -15.f), 15.f);      // overflow guard for fast tanh
        float e = __expf(2.f * v);
        float h = (e - 1.f) / (e + 1.f);
        bf16 hb = __float2bfloat16(h);
        dst_bf[(size_t)row * H_SZ + col] = hb;
        if (t == lens[row] - 1) yl[(size_t)row * H_SZ + col] = hb;
      } else if constexpr (MODE == 1) {
        v += bias[col];
        dst_bf[(size_t)row * H_SZ + col] = __float2bfloat16(fmaxf(v, 0.f));
      } else {
        if (col < C_SZ) outf[(size_t)row * C_SZ + col] = v + bias[col];
      }
    }
  }
}

// ---------------------------------------------------------------------------
// rnn_fused: 64 steps + FC1 + FC2, ONE dispatch, grid 256 (1 WG/CU).
// - w_hh slice pinned in LDS (128KB, invalidate-immune) -> no per-step B refetch
// - h rotates through 4 buffers; acquire-invalidate only when (t&3)==3:
//   buf b is read at steps t === b (mod 4); between consecutive reads (t-4, t)
//   there is exactly one acquire (end of the step === 3 mod 4 in that window),
//   after the t-4 read and before the t read -> no stale line can survive.
//   Local writes make lines dirty-fresh; remote writes are MALL-published by
//   the writer's RELEASE before the counter reaches target.
// - XCD-aligned clusters (perf-only): mb=(bid&7)*2+((bid>>3)&1) puts all 16
//   WGs of a cluster on one XCD under round-robin dispatch.
// ---------------------------------------------------------------------------
__global__ __launch_bounds__(256) void rnn_fused_kernel(
    const float* __restrict__ b_hh, const float* __restrict__ fc1_b,
    const float* __restrict__ fc2_b, const int* __restrict__ lens,
    char* __restrict__ ws, float* __restrict__ out) {
  extern __shared__ char smem[];
  bf16* Bsm = (bf16*)smem;                 // [64][1024] pinned weights, 128 KB
  bf16* Ap  = (bf16*)(smem + 131072);      // 4 x [32][64] A pipe, 16 KB

  const int tid = threadIdx.x;
  const int lane = tid & 63, wid = tid >> 6;
  const int bid = blockIdx.x;
  const int mb = ((bid & 7) << 1) | ((bid >> 3) & 1);  // row-cluster (XCD-aligned)
  const int nb = bid >> 4;                             // 16 col slices of 64
  const int rowBase = mb * 32, colBase = nb * 64;

  const bf16* whh  = (const bf16*)(ws + WHH_OFF);
  const bf16* fc1w = (const bf16*)(ws + FC1_OFF);
  const bf16* fc2w = (const bf16*)(ws + FC2_OFF);
  const bf16* xp   = (const bf16*)(ws + XP_OFF);
  bf16* hb = (bf16*)(ws + HB_OFF);
  bf16* yl = (bf16*)(ws + EMB_OFF);   // emb dead after xproj
  bf16* y1 = (bf16*)(ws + WIH_OFF);   // w_ih dead after xproj
  unsigned* bar = (unsigned*)(ws + BAR_OFF + (size_t)mb * 128);

  // pin w_hh slice
  stage_pinB(whh, Bsm, lane, wid, colBase);
  asm volatile("s_waitcnt vmcnt(0)" ::: "memory");
  __builtin_amdgcn_s_barrier();
  asm volatile("" ::: "memory");

  unsigned ep = 0;
#pragma unroll 1
  for (int t = 0; t < S_SZ; ++t) {
    const bf16* hsrc = hb + ((size_t)(t & 3) << 19);
    bf16* hdst = hb + ((size_t)((t + 1) & 3) << 19);
    phase<0>(hsrc, Bsm, Ap, lane, wid, rowBase, colBase, b_hh,
             xp + (size_t)t * (B_SZ * H_SZ), lens, t, hdst, yl, nullptr);
    ++ep;
    clusterbar(bar, ep * 16u, (t & 3) == 3);
  }

  // FC1 (relu) — re-pin B with fc1 slice
  stage_pinB(fc1w, Bsm, lane, wid, colBase);
  asm volatile("s_waitcnt vmcnt(0)" ::: "memory");
  __builtin_amdgcn_s_barrier();
  asm volatile("" ::: "memory");
  phase<1>(yl, Bsm, Ap, lane, wid, rowBase, colBase, fc1_b,
           nullptr, nullptr, 0, y1, nullptr, nullptr);
  ++ep;
  clusterbar(bar, ep * 16u, true);

  // FC2 — re-pin B with fc2 slice (pad rows >=1000 are zeros/counters; those
  // columns are discarded at the store)
  stage_pinB(fc2w, Bsm, lane, wid, colBase);
  asm volatile("s_waitcnt vmcnt(0)" ::: "memory");
  __builtin_amdgcn_s_barrier();
  asm volatile("" ::: "memory");
  phase<2>(y1, Bsm, Ap, lane, wid, rowBase, colBase, fc2_b,
           nullptr, nullptr, 0, nullptr, nullptr, out);
}

// ---------------------------------------------------------------------------
extern "C" void kernel_launch(void* const* d_in, const int* in_sizes, int n_in,
                              void* d_out, int out_size, void* d_ws, size_t ws_size,
                              hipStream_t stream) {
  (void)in_sizes; (void)n_in; (void)out_size; (void)ws_size;
  const int* x_in = (const int*)d_in[0];
  const int* x_len = (const int*)d_in[1];
  const float* emb_w = (const float*)d_in[2];
  const float* w_ih = (const float*)d_in[3];
  const float* b_ih = (const float*)d_in[4];
  const float* w_hh = (const float*)d_in[5];
  const float* b_hh = (const float*)d_in[6];
  const float* fc1_w = (const float*)d_in[7];
  const float* fc1_b = (const float*)d_in[8];
  const float* fc2_w = (const float*)d_in[9];
  const float* fc2_b = (const float*)d_in[10];
  char* ws = (char*)d_ws;
  float* out = (float*)d_out;

  // 1) weights -> bf16, zero h_buf0, zero fc2 pads (incl. barrier counters)
  prep_kernel<<<2048, 256, 0, stream>>>(emb_w, w_ih, w_hh, fc1_w, fc2_w, ws);

  // 2) x_proj GEMM (gathered A)
  xproj_kernel<<<2048, 256, 0, stream>>>(x_in, b_ih, ws);

  // 3) fused RNN + FC1 + FC2 with 144KB dynamic LDS (B-pin + A pipe)
  (void)hipFuncSetAttribute((const void*)rnn_fused_kernel,
                            hipFuncAttributeMaxDynamicSharedMemorySize, 147456);
  rnn_fused_kernel<<<256, 256, 147456, stream>>>(b_hh, fc1_b, fc2_b, x_len, ws, out);
}

// Round 8
// 629.713 us; speedup vs baseline: 2.5068x; 1.1712x over previous
//
#include <hip/hip_runtime.h>
#include <hip/hip_bf16.h>
#include <stdint.h>
#include <stddef.h>

// Problem sizes (fixed by the reference)
#define B_SZ 512
#define S_SZ 64
#define E_SZ 512
#define H_SZ 1024
#define V_SZ 1024
#define C_SZ 1000

typedef __hip_bfloat16 bf16;
typedef __attribute__((ext_vector_type(8))) __bf16 bf16x8;
typedef __attribute__((ext_vector_type(4))) float f32x4;

// ---- workspace layout (bytes), total 76 MB (same proven bound) ----
#define EMB_OFF   (0ull)          // emb bf16 (xproj input); REUSED as yl [512][1024] by fused
#define WIH_OFF   (1ull << 20)    // w_ih bf16 (xproj input); REUSED as y1 by fused
#define WHH_OFF   (2ull << 20)    // w_hh  bf16 [1024][1024] 2 MB
#define FC1_OFF   (4ull << 20)    // fc1_w bf16 [1024][1024] 2 MB
#define FC2_OFF   (6ull << 20)    // fc2_w bf16 [1024][1024] 2 MB (rows >=1000 zero)
#define HB_OFF    (8ull << 20)    // 4 rotating h bufs, 1 MB each; buf0 zeroed by prep
#define XP_OFF    (12ull << 20)   // x_proj bf16 [64][512][1024] 64 MB
// 16 cluster counters, 128B apart, in fc2 zero-pad rows (read only as discarded-col weights)
#define BAR_OFF   (FC2_OFF + 2048000ull)

// async global->LDS, 16B/lane; lane l lands at lds_base + l*16 (linear).
__device__ __forceinline__ void gl_lds16(const void* g, void* l) {
  __builtin_amdgcn_global_load_lds(
      (const __attribute__((address_space(1))) unsigned int*)g,
      (__attribute__((address_space(3))) unsigned int*)l, 16, 0, 0);
}

// ---------------------------------------------------------------------------
// prep: fp32 -> bf16 weights + zero h_buf0 + zero fc2 pad rows (incl counters)
// ---------------------------------------------------------------------------
__global__ __launch_bounds__(256) void prep_kernel(
    const float* __restrict__ emb_w, const float* __restrict__ w_ih,
    const float* __restrict__ w_hh, const float* __restrict__ fc1_w,
    const float* __restrict__ fc2_w, char* __restrict__ ws) {
  bf16* emb = (bf16*)(ws + EMB_OFF);
  bf16* wih = (bf16*)(ws + WIH_OFF);
  bf16* whh = (bf16*)(ws + WHH_OFF);
  bf16* fc1 = (bf16*)(ws + FC1_OFF);
  bf16* fc2 = (bf16*)(ws + FC2_OFF);
  bf16* h0  = (bf16*)(ws + HB_OFF);

  const long N_EMB = 524288, N_WIH = 524288, N_WHH = 1048576;
  const long N_FC1 = 1048576, N_FC2 = 1048576, N_H0 = 524288;
  const long TOTAL = N_EMB + N_WIH + N_WHH + N_FC1 + N_FC2 + N_H0;

  long stride = (long)gridDim.x * blockDim.x;
  for (long i = (long)blockIdx.x * blockDim.x + threadIdx.x; i < TOTAL; i += stride) {
    long j = i;
    if (j < N_EMB) {  // row 0 forced zero (PAD row)
      emb[j] = (j < E_SZ) ? __float2bfloat16(0.f) : __float2bfloat16(emb_w[j]);
      continue;
    }
    j -= N_EMB;
    if (j < N_WIH) { wih[j] = __float2bfloat16(w_ih[j]); continue; }
    j -= N_WIH;
    if (j < N_WHH) { whh[j] = __float2bfloat16(w_hh[j]); continue; }
    j -= N_WHH;
    if (j < N_FC1) { fc1[j] = __float2bfloat16(fc1_w[j]); continue; }
    j -= N_FC1;
    if (j < N_FC2) {
      fc2[j] = (j < (long)C_SZ * H_SZ) ? __float2bfloat16(fc2_w[j]) : __float2bfloat16(0.f);
      continue;
    }
    j -= N_FC2;
    h0[j] = __float2bfloat16(0.f);
  }
}

// ---------------------------------------------------------------------------
// xproj (unchanged, proven: 46.6us, 0 bank conflicts)
// ---------------------------------------------------------------------------
__global__ __launch_bounds__(256) void xproj_kernel(
    const int* __restrict__ x_in, const float* __restrict__ b_ih,
    char* __restrict__ ws) {
  const bf16* emb = (const bf16*)(ws + EMB_OFF);
  const bf16* wih = (const bf16*)(ws + WIH_OFF);
  bf16* xp = (bf16*)(ws + XP_OFF);

  __shared__ bf16 Asm[2][128][64];
  __shared__ bf16 Bsm[2][128][64];

  const int tid = threadIdx.x;
  const int lane = tid & 63;
  const int wid = tid >> 6;
  const int mb = blockIdx.x >> 3;
  const int nb = blockIdx.x & 7;
  const int rowBase = mb * 128;
  const int colBase = nb * 128;
  const int s = rowBase >> 9;

  const int lrow = lane >> 3;
  const int lchk = lane & 7;

  int tok[4];
#pragma unroll
  for (int i = 0; i < 4; ++i) {
    int rt = wid * 32 + i * 8 + lrow;
    int b = (rowBase + rt) & 511;
    tok[i] = x_in[b * S_SZ + s];
  }

  const int wr = wid >> 1, wc = wid & 1;
  f32x4 acc[4][4];
#pragma unroll
  for (int i = 0; i < 4; ++i)
#pragma unroll
    for (int j = 0; j < 4; ++j) acc[i][j] = (f32x4){0.f, 0.f, 0.f, 0.f};

  auto stage = [&](int buf, int k0) {
#pragma unroll
    for (int i = 0; i < 4; ++i) {
      int rt = wid * 32 + i * 8;
      int sc = (lchk ^ ((rt + lrow) & 7)) * 8;
      gl_lds16(emb + (size_t)tok[i] * E_SZ + k0 + sc, &Asm[buf][rt][0]);
    }
#pragma unroll
    for (int i = 0; i < 4; ++i) {
      int rt = wid * 32 + i * 8;
      int sc = (lchk ^ ((rt + lrow) & 7)) * 8;
      gl_lds16(wih + (size_t)(colBase + rt + lrow) * E_SZ + k0 + sc, &Bsm[buf][rt][0]);
    }
  };

  stage(0, 0);
  __syncthreads();
  int cur = 0;
  for (int t8 = 0; t8 < 8; ++t8) {
    if (t8 < 7) stage(cur ^ 1, (t8 + 1) * 64);
#pragma unroll
    for (int kk = 0; kk < 2; ++kk) {
      const int kfc = kk * 4 + (lane >> 4);
      bf16x8 a[4], b[4];
#pragma unroll
      for (int i = 0; i < 4; ++i) {
        int r = wr * 64 + i * 16 + (lane & 15);
        a[i] = *(const bf16x8*)&Asm[cur][r][(kfc ^ (r & 7)) * 8];
      }
#pragma unroll
      for (int j = 0; j < 4; ++j) {
        int r = wc * 64 + j * 16 + (lane & 15);
        b[j] = *(const bf16x8*)&Bsm[cur][r][(kfc ^ (r & 7)) * 8];
      }
#pragma unroll
      for (int i = 0; i < 4; ++i)
#pragma unroll
        for (int j = 0; j < 4; ++j)
          acc[i][j] = __builtin_amdgcn_mfma_f32_16x16x32_bf16(a[i], b[j], acc[i][j], 0, 0, 0);
    }
    __syncthreads();
    cur ^= 1;
  }

  const int crow = (lane >> 4) * 4;
  const int ccol = lane & 15;
#pragma unroll
  for (int j = 0; j < 4; ++j) {
    const int col = colBase + wc * 64 + j * 16 + ccol;
    const float bias = b_ih[col];
#pragma unroll
    for (int i = 0; i < 4; ++i) {
      const int r0 = rowBase + wr * 64 + i * 16 + crow;
#pragma unroll
      for (int reg = 0; reg < 4; ++reg) {
        float v = acc[i][j][reg] + bias;
        xp[(size_t)(r0 + reg) * H_SZ + col] = __float2bfloat16(v);
      }
    }
  }
}

// ---------------------------------------------------------------------------
// Cluster barrier (fan-in 16) — byte-identical mechanics to round 7 (proven).
// ---------------------------------------------------------------------------
__device__ __forceinline__ void clusterbar(unsigned* bar, unsigned target, bool acq) {
  __syncthreads();
  if (threadIdx.x == 0) {
    __hip_atomic_fetch_add(bar, 1u, __ATOMIC_RELEASE, __HIP_MEMORY_SCOPE_AGENT);
    while (__hip_atomic_load(bar, __ATOMIC_RELAXED, __HIP_MEMORY_SCOPE_AGENT) < target)
      __builtin_amdgcn_s_sleep(1);
    if (acq)
      (void)__hip_atomic_load(bar, __ATOMIC_ACQUIRE, __HIP_MEMORY_SCOPE_AGENT);
  }
  asm volatile("" ::: "memory");
  __syncthreads();
}

// ---------------------------------------------------------------------------
// Load this thread's 32 B-fragments (out-col c0, all K=1024) into registers.
// B fragment layout per lane (m89-proven): row (lane&15 within tile), k-chunk
// (kk*4 + lane>>4)*8 — i.e. 16B at w[c0][i*64 + kk*32 + (lane>>4)*8].
// Registers are invalidate-immune: no B re-read for the whole RNN loop.
// ---------------------------------------------------------------------------
__device__ __forceinline__ void load_breg(bf16x8 (&breg)[16][2],
                                          const bf16* w, int c0, int lane) {
  const bf16* wrow = w + (size_t)c0 * H_SZ + ((lane >> 4) << 3);
#pragma unroll
  for (int i = 0; i < 16; ++i)
#pragma unroll
    for (int kk = 0; kk < 2; ++kk)
      breg[i][kk] = *(const bf16x8*)(wrow + i * 64 + kk * 32);
}

// ---------------------------------------------------------------------------
// phase: one 32x64 tile (8 waves; per wave 16x16, wr=wid&1, wc=wid>>1),
// K=1024 in 16 blocks of 64. A staged into fragment-PACKED LDS (lane-major
// 16B = exactly gl_lds16's linear write) -> every ds_read_b128 is stride-1,
// zero bank conflicts. Waves 0..3 are stagers: wave w stages fragment
// (swr=w&1, skk=w>>1), 1 op (1KB) per iter, counted vmcnt (r7-proven math:
// stage for buf i+3 issued after barrier i; vmcnt(2) at iter i => op i done).
// B comes entirely from breg registers.
// MODE 0: h=tanh(acc+xp+b); capture yl.  1: relu->bf16.  2: fp32 out (<1000).
// ---------------------------------------------------------------------------
template <int MODE>
__device__ __forceinline__ void phase(
    const bf16* __restrict__ Asrc, const bf16x8 (&breg)[16][2], bf16* Ap,
    int lane, int wid, int rowBase, float bias_v,
    const bf16 (&xv)[4], const int (&lenv)[4], int t, int r0, int c0,
    bf16* __restrict__ dst, bf16* __restrict__ yl, float* __restrict__ outf) {
  const int wr = wid & 1;
  f32x4 acc = (f32x4){0.f, 0.f, 0.f, 0.f};

  // stager addressing (valid for wid<4): frag (swr=wid&1, skk=wid>>1)
  const bf16* sbase = Asrc +
      (size_t)(rowBase + (wid & 1) * 16 + (lane & 15)) * H_SZ +
      (wid >> 1) * 32 + ((lane >> 4) << 3);
  bf16* sdst0 = Ap + ((wid & 1) * 2 + (wid >> 1)) * 512;  // + buf*2048

  if (wid < 4) {  // prologue: 3 bufs in flight
    gl_lds16(sbase, sdst0);
    asm volatile("" ::: "memory");
    gl_lds16(sbase + 64, sdst0 + 2048);
    asm volatile("" ::: "memory");
    gl_lds16(sbase + 128, sdst0 + 2 * 2048);
  }

#pragma unroll
  for (int i = 0; i < 16; ++i) {
    if (wid < 4) {
      if (i < 14)       asm volatile("s_waitcnt vmcnt(2)" ::: "memory");
      else if (i == 14) asm volatile("s_waitcnt vmcnt(1)" ::: "memory");
      else              asm volatile("s_waitcnt vmcnt(0)" ::: "memory");
    }
    __builtin_amdgcn_s_barrier();
    asm volatile("" ::: "memory");
    if (wid < 4 && i < 13)
      gl_lds16(sbase + (i + 3) * 64, sdst0 + ((i + 3) & 3) * 2048);
    const bf16* Ab = Ap + (i & 3) * 2048 + wr * 1024 + lane * 8;
    bf16x8 a0 = *(const bf16x8*)(Ab);          // frag (wr, kk=0), stride-1
    bf16x8 a1 = *(const bf16x8*)(Ab + 512);    // frag (wr, kk=1)
    acc = __builtin_amdgcn_mfma_f32_16x16x32_bf16(a0, breg[i][0], acc, 0, 0, 0);
    acc = __builtin_amdgcn_mfma_f32_16x16x32_bf16(a1, breg[i][1], acc, 0, 0, 0);
  }

  // epilogue (D map: col=lane&15, row=(lane>>4)*4+reg — m89-verified)
#pragma unroll
  for (int reg = 0; reg < 4; ++reg) {
    const int row = r0 + reg;
    float v = acc[reg];
    if constexpr (MODE == 0) {
      v += bias_v + __bfloat162float(xv[reg]);
      v = fminf(fmaxf(v, -15.f), 15.f);      // overflow guard for fast tanh
      float e = __expf(2.f * v);
      float h = (e - 1.f) / (e + 1.f);
      bf16 hb = __float2bfloat16(h);
      dst[(size_t)row * H_SZ + c0] = hb;
      if (t == lenv[reg] - 1) yl[(size_t)row * H_SZ + c0] = hb;
    } else if constexpr (MODE == 1) {
      dst[(size_t)row * H_SZ + c0] = __float2bfloat16(fmaxf(v + bias_v, 0.f));
    } else {
      if (c0 < C_SZ) outf[(size_t)row * C_SZ + c0] = v + bias_v;
    }
  }
}

// ---------------------------------------------------------------------------
// rnn_fused: 64 steps + FC1 + FC2, ONE dispatch, grid 256 x 512thr (8 waves,
// 2 waves/SIMD — 2x round-7 occupancy). w_hh/fc1/fc2 fragments in REGISTERS
// (128 VGPR), A fragment-packed in 16KB LDS. h 4-buf rotation + acquire every
// 4th step + cluster-barrier mechanics unchanged from round 7 (proven).
// XCD-aligned clusters (perf-only): mb=(bid&7)*2+((bid>>3)&1).
// ---------------------------------------------------------------------------
__global__ __launch_bounds__(512, 2) void rnn_fused_kernel(
    const float* __restrict__ b_hh, const float* __restrict__ fc1_b,
    const float* __restrict__ fc2_b, const int* __restrict__ lens,
    char* __restrict__ ws, float* __restrict__ out) {
  __shared__ bf16 Ap[8192];  // 4 bufs x 4KB fragment-packed A pipe (16 KB)

  const int tid = threadIdx.x;
  const int lane = tid & 63, wid = tid >> 6;
  const int bid = blockIdx.x;
  const int mb = ((bid & 7) << 1) | ((bid >> 3) & 1);  // row-cluster (XCD-aligned)
  const int nb = bid >> 4;                             // 16 col slices of 64
  const int rowBase = mb * 32;
  const int colBase = nb * 64;
  const int wr = wid & 1, wc = wid >> 1;
  const int r0 = rowBase + wr * 16 + ((lane >> 4) << 2);
  const int c0 = colBase + wc * 16 + (lane & 15);

  const bf16* whh  = (const bf16*)(ws + WHH_OFF);
  const bf16* fc1w = (const bf16*)(ws + FC1_OFF);
  const bf16* fc2w = (const bf16*)(ws + FC2_OFF);
  const bf16* xp   = (const bf16*)(ws + XP_OFF);
  bf16* hb = (bf16*)(ws + HB_OFF);
  bf16* yl = (bf16*)(ws + EMB_OFF);   // emb dead after xproj
  bf16* y1 = (bf16*)(ws + WIH_OFF);   // w_ih dead after xproj
  unsigned* bar = (unsigned*)(ws + BAR_OFF + (size_t)mb * 128);

  // per-thread invariants hoisted out of the 64-step loop
  const float bhv = b_hh[c0];
  int lenv[4];
#pragma unroll
  for (int reg = 0; reg < 4; ++reg) lenv[reg] = lens[r0 + reg];

  bf16x8 breg[16][2];
  load_breg(breg, whh, c0, lane);

  bf16 xv[4];
#pragma unroll
  for (int reg = 0; reg < 4; ++reg) xv[reg] = xp[(size_t)(r0 + reg) * H_SZ + c0];

#pragma unroll 1
  for (int t = 0; t < S_SZ; ++t) {
    const bf16* hsrc = hb + ((size_t)(t & 3) << 19);
    bf16* hdst = hb + ((size_t)((t + 1) & 3) << 19);
    phase<0>(hsrc, breg, Ap, lane, wid, rowBase, bhv, xv, lenv, t, r0, c0,
             hdst, yl, nullptr);
    if (t < S_SZ - 1) {  // hoist next-step xp fragment before the barrier
      const bf16* xpn = xp + (size_t)(t + 1) * (B_SZ * H_SZ);
#pragma unroll
      for (int reg = 0; reg < 4; ++reg)
        xv[reg] = xpn[(size_t)(r0 + reg) * H_SZ + c0];
    }
    clusterbar(bar, (unsigned)(t + 1) * 16u, (t & 3) == 3);
  }

  // FC1 (relu): B = fc1 fragments in regs
  load_breg(breg, fc1w, c0, lane);
  const float b1v = fc1_b[c0];
  phase<1>(yl, breg, Ap, lane, wid, rowBase, b1v, xv, lenv, 0, r0, c0,
           y1, nullptr, nullptr);
  clusterbar(bar, 65u * 16u, true);

  // FC2: B = fc2 fragments (pad rows >=1000 are zeros/counters; those output
  // columns are discarded at the store — per-output-col independence of MFMA)
  load_breg(breg, fc2w, c0, lane);
  const float b2v = (c0 < C_SZ) ? fc2_b[c0] : 0.f;
  phase<2>(y1, breg, Ap, lane, wid, rowBase, b2v, xv, lenv, 0, r0, c0,
           nullptr, nullptr, out);
}

// ---------------------------------------------------------------------------
extern "C" void kernel_launch(void* const* d_in, const int* in_sizes, int n_in,
                              void* d_out, int out_size, void* d_ws, size_t ws_size,
                              hipStream_t stream) {
  (void)in_sizes; (void)n_in; (void)out_size; (void)ws_size;
  const int* x_in = (const int*)d_in[0];
  const int* x_len = (const int*)d_in[1];
  const float* emb_w = (const float*)d_in[2];
  const float* w_ih = (const float*)d_in[3];
  const float* b_ih = (const float*)d_in[4];
  const float* w_hh = (const float*)d_in[5];
  const float* b_hh = (const float*)d_in[6];
  const float* fc1_w = (const float*)d_in[7];
  const float* fc1_b = (const float*)d_in[8];
  const float* fc2_w = (const float*)d_in[9];
  const float* fc2_b = (const float*)d_in[10];
  char* ws = (char*)d_ws;
  float* out = (float*)d_out;

  // 1) weights -> bf16, zero h_buf0, zero fc2 pads (incl. barrier counters)
  prep_kernel<<<2048, 256, 0, stream>>>(emb_w, w_ih, w_hh, fc1_w, fc2_w, ws);

  // 2) x_proj GEMM (gathered A)
  xproj_kernel<<<2048, 256, 0, stream>>>(x_in, b_ih, ws);

  // 3) fused RNN + FC1 + FC2: 8-wave WGs, reg-B, packed-LDS A
  rnn_fused_kernel<<<256, 512, 0, stream>>>(b_hh, fc1_b, fc2_b, x_len, ws, out);
}